// Round 6
// baseline (233.997 us; speedup 1.0000x reference)
//
#include <hip/hip_runtime.h>
#include <stdint.h>

#pragma clang fp contract(off)

#define NCELL 49
#define NCLS  20

struct Box { float x1, y1, x2, y2; };

__device__ __forceinline__ float sigmoid_ref(float x) {
#pragma clang fp contract(off)
  if (x >= 0.0f) {
    float z = expf(-x);
    return 1.0f / (1.0f + z);
  } else {
    float z = expf(x);
    return z / (1.0f + z);
  }
}

__device__ __forceinline__ float iou_box(Box a, Box b) {
#pragma clang fp contract(off)
  float lx = fmaxf(a.x1, b.x1);
  float ly = fmaxf(a.y1, b.y1);
  float rx = fminf(a.x2, b.x2);
  float ry = fminf(a.y2, b.y2);
  float w = fmaxf(rx - lx, 0.0f);
  float h = fmaxf(ry - ly, 0.0f);
  float inter = w * h;
  float aa = (a.x2 - a.x1) * (a.y2 - a.y1);
  float ab = (b.x2 - b.x1) * (b.y2 - b.y1);
  return inter / (aa + ab - inter);
}

__device__ __forceinline__ float permf(int dst, float v) {
  return __int_as_float(__builtin_amdgcn_ds_permute(dst << 2, __float_as_int(v)));
}
// uniform-lane broadcast: pure VALU (no LDS crossbar)
__device__ __forceinline__ float rlf(float v, int i) {
  return __int_as_float(__builtin_amdgcn_readlane(__float_as_int(v), i));
}
__device__ __forceinline__ int rli(int v, int i) {
  return __builtin_amdgcn_readlane(v, i);
}
__device__ __forceinline__ unsigned mbcnt64(unsigned long long m) {
  return __builtin_amdgcn_mbcnt_hi((unsigned)(m >> 32),
         __builtin_amdgcn_mbcnt_lo((unsigned)m, 0u));
}

// One wave per image; 4 images per 256-thread block. LDS only for the
// one-time rank scatter; all broadcasts are readlane (VALU).
__global__ __launch_bounds__(256) void k_per_image(
    const float* __restrict__ target, const float* __restrict__ output,
    uint8_t* __restrict__ entries, int* __restrict__ gt_count, int batch)
{
#pragma clang fp contract(off)
  int lane = threadIdx.x & 63;
  int img  = blockIdx.x * 4 + (threadIdx.x >> 6);
  if (img >= batch) return;            // uniform per wave
  bool a = lane < NCELL;

  // ---- per-lane direct loads: 15+15 independent float2 (8B-aligned) ----
  float tv[30], ov[30];
  if (a) {
    const float2* T2 = (const float2*)(target + (size_t)img * 1470 + lane * 30);
    const float2* O2 = (const float2*)(output + (size_t)img * 1470 + lane * 30);
#pragma unroll
    for (int i = 0; i < 15; ++i) { float2 t = T2[i]; tv[2*i] = t.x; tv[2*i+1] = t.y; }
#pragma unroll
    for (int i = 0; i < 15; ++i) { float2 o = O2[i]; ov[2*i] = o.x; ov[2*i+1] = o.y; }
  } else {
#pragma unroll
    for (int i = 0; i < 30; ++i) { tv[i] = 0.0f; ov[i] = 0.0f; }
  }

  float fjx = (float)(lane % 7), fiy = (float)(lane / 7);

  // ---- ground truth (raw target, no sigmoid) ----
  int gcls = 0; float gx1 = 0, gy1 = 0, gx2 = 0, gy2 = 0; bool gval = false;
  if (a) {
    float tbv = tv[10];
#pragma unroll
    for (int c = 1; c < NCLS; ++c) { float v = tv[10 + c]; if (v > tbv) { tbv = v; gcls = c; } }
    gval = tv[4] > 0.5f;
    float cx = (tv[0] + fjx) * 64.0f, cy = (tv[1] + fiy) * 64.0f;
    float w = tv[2] * 448.0f, h = tv[3] * 448.0f;
    gx1 = cx - w * 0.5f; gy1 = cy - h * 0.5f;
    gx2 = cx + w * 0.5f; gy2 = cy + h * 0.5f;
  }
  unsigned long long gvmask = __ballot(a && gval);

  // ---- gt_count via per-class ballots, one atomic per (wave,class) ----
  {
    int mycnt = 0;
#pragma unroll 1
    for (int c = 0; c < NCLS; ++c) {
      unsigned long long m = __ballot(a && gval && (gcls == c));
      if (lane == c) mycnt = (int)__popcll(m);
    }
    if (lane < NCLS && mycnt) atomicAdd(&gt_count[lane], mycnt);
  }

  // ---- predictions (sigmoid everything, identical formula) ----
  float myc = -1.0f; int myk = 0; float px1 = 0, py1 = 0, px2 = 0, py2 = 0;
  if (a) {
#pragma unroll
    for (int i = 0; i < 30; ++i) ov[i] = sigmoid_ref(ov[i]);
    float c0 = ov[4], c1 = ov[9];
    myc = fmaxf(c0, c1);
    int resp = (c1 > c0) ? 1 : 0;      // first max wins
    float x = ov[resp * 5 + 0], y = ov[resp * 5 + 1];
    float w = ov[resp * 5 + 2], h = ov[resp * 5 + 3];
    float obv = ov[10];
#pragma unroll
    for (int c = 1; c < NCLS; ++c) { float v = ov[10 + c]; if (v > obv) { obv = v; myk = c; } }
    float cx = (x + fjx) * 64.0f, cy = (y + fiy) * 64.0f;
    float W = w * 448.0f, H = h * 448.0f;
    px1 = cx - W * 0.5f; py1 = cy - H * 0.5f;
    px2 = cx + W * 0.5f; py2 = cy + H * 0.5f;
  }

  // ---- stable rank (argsort(-conf), index tiebreak): pipelined readlanes ----
  int r = 0;
#pragma unroll 7
  for (int j = 0; j < NCELL; ++j) {
    float cj = rlf(myc, j);
    r += (cj > myc) || (cj == myc && j < lane);
  }
  r = a ? r : lane;                    // identity for pad lanes (ranks 49..63)

  // ---- scatter to rank order (one-time, 6 LDS-crossbar ops) ----
  float sx1 = permf(r, px1), sy1 = permf(r, py1);
  float sx2 = permf(r, px2), sy2 = permf(r, py2);
  float sconf = permf(r, myc);
  int   scls  = __builtin_amdgcn_ds_permute(r << 2, myk);
  Box myS; myS.x1 = sx1; myS.y1 = sy1; myS.x2 = sx2; myS.y2 = sy2;

  // ---- phase 1: dependence-free candidate-suppression mask ----
  unsigned long long candmask = 0;
#pragma unroll 7
  for (int i = 0; i < NCELL; ++i) {
    Box bi;
    bi.x1 = rlf(sx1, i); bi.y1 = rlf(sy1, i);
    bi.x2 = rlf(sx2, i); bi.y2 = rlf(sy2, i);
    int ki = rli(scls, i);
    float v = iou_box(myS, bi);
    if (a && (lane > i) && (scls == ki) && (v > 0.5f)) candmask |= (1ull << i);
  }

  // ---- phase 2: serial NMS resolve (ballot + scalar only) ----
  unsigned long long sup = 0;
#pragma unroll 1
  for (int i = 0; i < NCELL; ++i) {
    if (!((sup >> i) & 1ull)) {
      sup |= __ballot((candmask >> i) & 1ull);
    }
  }

  bool vp = a && !((sup >> lane) & 1ull) && (sconf > 0.5f);

  // ---- best same-class GT per pred: pipelined readlanes, first-max ----
  float mx = -1.0f; int best = 0;
#pragma unroll 7
  for (int g = 0; g < NCELL; ++g) {
    Box bg;
    bg.x1 = rlf(gx1, g); bg.y1 = rlf(gy1, g);
    bg.x2 = rlf(gx2, g); bg.y2 = rlf(gy2, g);
    int kg = rli(gcls, g);
    float v = iou_box(myS, bg);
    bool upd = a && ((gvmask >> g) & 1ull) && (scls == kg) && (v > mx);
    if (upd) { mx = v; best = g; }
  }

  // ---- greedy TP assignment: scalar chain via readlane ----
  unsigned long long vpmask = __ballot(vp);
  unsigned long long matched = 0, hits = 0;
#pragma unroll 1
  for (int i = 0; i < NCELL; ++i) {
    if ((vpmask >> i) & 1ull) {
      float mxi = rlf(mx, i);
      int   bi  = rli(best, i);
      if ((mxi > 0.5f) && !((matched >> bi) & 1ull)) {
        matched |= 1ull << bi;
        hits    |= 1ull << i;
      }
    }
  }

  if (a) {
    entries[(size_t)img * NCELL + lane] =
        (uint8_t)(scls | (vp ? 32 : 0) | (((hits >> lane) & 1ull) ? 64 : 0));
  }
}

// Exact per-byte match: y bytes < 0x40, so per-byte (y+0x7f) sets bit7 iff
// y>=1 with NO cross-byte carry. m has 0x80 exactly where (b&0x3f)==want.
__device__ __forceinline__ unsigned match_mask(unsigned w, unsigned wantx4) {
  unsigned y = (w & 0x3f3f3f3fu) ^ wantx4;
  return ~(y + 0x7f7f7f7fu) & 0x80808080u;
}

// One block per class; coalesced lane-interleaved 16B tiles. Phase A:
// per-wave totals. Phase B: per-tile prefix via bit-plane ballot+mbcnt
// (pure VALU — no shuffle chains); SWAR match + sparse emit.
__global__ __launch_bounds__(256) void k_ap(
    const uint8_t* __restrict__ entries, const int* __restrict__ gt_count,
    float* __restrict__ ap_out, int ne)
{
#pragma clang fp contract(off)
  int c = blockIdx.x, tid = threadIdx.x, wid = tid >> 6, lane = tid & 63;
  float g2 = (float)gt_count[c] + 1e-6f;
  unsigned wantx4 = (32u + (unsigned)c) * 0x01010101u;

  int nel = (ne + 15) >> 4;          // 16B elements total
  int elw = (nel + 3) >> 2;          // elements per wave
  int e0 = wid * elw;
  int e1 = e0 + elw; if (e1 > nel) e1 = nel;
  int ntile = (e1 > e0) ? ((e1 - e0 + 63) >> 6) : 0;

  __shared__ unsigned long long wt[4];
  __shared__ double wacc[4];

  // ---- phase A: per-wave (valid, tp) totals ----
  unsigned mv = 0, mt = 0;
  for (int t = 0; t < ntile; ++t) {
    int e = e0 + t * 64 + lane;
    uint4 w4 = make_uint4(0, 0, 0, 0);
    if (e < e1) {
      int p = e << 4;
      if (p + 16 <= ne) {
        w4 = *(const uint4*)(entries + p);
      } else {
        unsigned ws[4] = {0, 0, 0, 0};
        for (int k = 0; k < ne - p; ++k)
          ws[k >> 2] |= ((unsigned)entries[p + k]) << (8 * (k & 3));
        w4.x = ws[0]; w4.y = ws[1]; w4.z = ws[2]; w4.w = ws[3];
      }
    }
    unsigned wsv[4] = {w4.x, w4.y, w4.z, w4.w};
#pragma unroll
    for (int q = 0; q < 4; ++q) {
      unsigned w = wsv[q];
      unsigned m = match_mask(w, wantx4);
      mv += __popc(m);
      mt += __popc(m & (w << 1));                        // tp-bit (0x40)<<1
    }
  }
  unsigned long long tot = ((unsigned long long)mv << 32) | (unsigned long long)mt;
#pragma unroll
  for (int d = 1; d < 64; d <<= 1) tot += __shfl_xor(tot, d, 64);
  if (lane == 0) wt[wid] = tot;
  __syncthreads();
  unsigned Jrun = 0, Trun = 0;
  for (int w2 = 0; w2 < wid; ++w2) {
    Jrun += (unsigned)(wt[w2] >> 32);
    Trun += (unsigned)(wt[w2] & 0xffffffffull);
  }

  // ---- phase B: emit trapezoid terms with exact running ranks ----
  double acc = 0.0;
  for (int t = 0; t < ntile; ++t) {
    int e = e0 + t * 64 + lane;
    int p = e << 4;
    uint4 w4 = make_uint4(0, 0, 0, 0);
    if (e < e1) {
      if (p + 16 <= ne) {
        w4 = *(const uint4*)(entries + p);
      } else {
        unsigned ws[4] = {0, 0, 0, 0};
        for (int k = 0; k < ne - p; ++k)
          ws[k >> 2] |= ((unsigned)entries[p + k]) << (8 * (k & 3));
        w4.x = ws[0]; w4.y = ws[1]; w4.z = ws[2]; w4.w = ws[3];
      }
    }
    unsigned wsv[4] = {w4.x, w4.y, w4.z, w4.w};
    unsigned mm[4], tm[4];
    unsigned cv = 0, ct = 0;
#pragma unroll
    for (int q = 0; q < 4; ++q) {
      unsigned w = wsv[q];
      unsigned m = match_mask(w, wantx4);
      mm[q] = m; tm[q] = m & (w << 1);
      cv += __popc(m); ct += __popc(tm[q]);
    }
    // exclusive prefix over lanes via bit-plane ballots (cv,ct <= 16)
    unsigned jexcl = 0, texcl = 0, jtt = 0, ttt = 0;
#pragma unroll
    for (int b = 0; b < 5; ++b) {
      unsigned long long mj = __ballot(((cv >> b) & 1u) != 0u);
      unsigned long long mk = __ballot(((ct >> b) & 1u) != 0u);
      jexcl += mbcnt64(mj) << b;
      texcl += mbcnt64(mk) << b;
      jtt   += (unsigned)__popcll(mj) << b;
      ttt   += (unsigned)__popcll(mk) << b;
    }
    unsigned jr = Jrun + jexcl;
    unsigned tr = Trun + texcl;
#pragma unroll
    for (int q = 0; q < 4; ++q) {
      unsigned m = mm[q];
      while (m) {
        unsigned bit = (unsigned)__builtin_ctz(m);
        m &= m - 1;
        ++jr;
        if (tm[q] & (1u << bit)) {
          ++tr;
          int pos = p + 4 * q + (int)(bit >> 3);
          float ft = (float)tr, fj = (float)jr;
          float r_cur  = ft / g2;
          float r_prev = (ft - 1.0f) / g2;
          float p_cur  = ft / (fj + 1e-6f);
          float p_prev = (pos == 0) ? 1.0f
                                    : (ft - 1.0f) / ((fj - 1.0f) + 1e-6f);
          acc += (double)((r_cur - r_prev) * (p_cur + p_prev) * 0.5f);
        }
      }
    }
    Jrun += jtt;
    Trun += ttt;
  }

  for (int d = 32; d > 0; d >>= 1) acc += __shfl_down(acc, d, 64);
  if (lane == 0) wacc[wid] = acc;
  __syncthreads();
  if (tid == 0) ap_out[c] = (float)(wacc[0] + wacc[1] + wacc[2] + wacc[3]);
}

__global__ void k_final(const float* __restrict__ ap,
                        const int* __restrict__ gt_count,
                        float* __restrict__ out)
{
#pragma clang fp contract(off)
  if (threadIdx.x == 0 && blockIdx.x == 0) {
    float s = 0.0f, n = 0.0f;
    for (int c = 0; c < NCLS; ++c) {
      if (gt_count[c] > 0) { s += ap[c]; n += 1.0f; }
    }
    float nh = fmaxf(n, 1.0f);
    out[0] = s / nh;
  }
}

extern "C" void kernel_launch(void* const* d_in, const int* in_sizes, int n_in,
                              void* d_out, int out_size, void* d_ws, size_t ws_size,
                              hipStream_t stream) {
  const float* target = (const float*)d_in[0];
  const float* output = (const float*)d_in[1];
  int batch = in_sizes[0] / (NCELL * 30);
  int ne = batch * NCELL;

  uint8_t* entries = (uint8_t*)d_ws;
  size_t off = ((size_t)ne + 255) & ~(size_t)255;
  int*   gt_count = (int*)((char*)d_ws + off);
  float* ap       = (float*)((char*)d_ws + off + 64 * sizeof(int));

  (void)hipMemsetAsync(gt_count, 0, 64 * sizeof(int), stream);
  k_per_image<<<(batch + 3) / 4, 256, 0, stream>>>(target, output, entries, gt_count, batch);
  k_ap<<<NCLS, 256, 0, stream>>>(entries, gt_count, ap, ne);
  k_final<<<1, 64, 0, stream>>>(ap, gt_count, (float*)d_out);
}

// Round 7
// 170.087 us; speedup vs baseline: 1.3758x; 1.3758x over previous
//
#include <hip/hip_runtime.h>
#include <stdint.h>

#pragma clang fp contract(off)

#define NCELL 49
#define NCLS  20
#define NSEG  16

struct Box { float x1, y1, x2, y2; };

__device__ __forceinline__ float sigmoid_ref(float x) {
#pragma clang fp contract(off)
  if (x >= 0.0f) {
    float z = expf(-x);
    return 1.0f / (1.0f + z);
  } else {
    float z = expf(x);
    return z / (1.0f + z);
  }
}

__device__ __forceinline__ float iou_box(Box a, Box b) {
#pragma clang fp contract(off)
  float lx = fmaxf(a.x1, b.x1);
  float ly = fmaxf(a.y1, b.y1);
  float rx = fminf(a.x2, b.x2);
  float ry = fminf(a.y2, b.y2);
  float w = fmaxf(rx - lx, 0.0f);
  float h = fmaxf(ry - ly, 0.0f);
  float inter = w * h;
  float aa = (a.x2 - a.x1) * (a.y2 - a.y1);
  float ab = (b.x2 - b.x1) * (b.y2 - b.y1);
  return inter / (aa + ab - inter);
}

__device__ __forceinline__ float permf(int dst, float v) {
  return __int_as_float(__builtin_amdgcn_ds_permute(dst << 2, __float_as_int(v)));
}
__device__ __forceinline__ unsigned mbcnt64(unsigned long long m) {
  return __builtin_amdgcn_mbcnt_hi((unsigned)(m >> 32),
         __builtin_amdgcn_mbcnt_lo((unsigned)m, 0u));
}

// 256 threads = 4 waves = 4 images. Coalesced float4 staging of 4 contiguous
// images into LDS (4 KB per staging instruction), then R5's shfl-based
// per-wave processing reading rows from LDS.
__global__ __launch_bounds__(256) void k_per_image(
    const float* __restrict__ target, const float* __restrict__ output,
    uint8_t* __restrict__ entries, int* __restrict__ gt_count, int batch)
{
#pragma clang fp contract(off)
  __shared__ __align__(16) float sTf[5880];
  __shared__ __align__(16) float sOf[5880];

  int tid = threadIdx.x;
  int lane = tid & 63;
  int w = tid >> 6;
  int img0 = blockIdx.x * 4;
  int img = img0 + w;

  // ---- coalesced staging ----
  {
    const size_t base = (size_t)img0 * 1470;
    if (img0 + 4 <= batch) {
      const float4* T4 = (const float4*)(target + base);
      const float4* O4 = (const float4*)(output + base);
      float4* sT4 = (float4*)sTf;
      float4* sO4 = (float4*)sOf;
#pragma unroll
      for (int u = 0; u < 6; ++u) {
        int j = tid + u * 256;
        if (j < 1470) { sT4[j] = T4[j]; sO4[j] = O4[j]; }
      }
    } else {
      int n = (batch - img0) * 1470;
      for (int j = tid; j < n; j += 256) { sTf[j] = target[base + j]; sOf[j] = output[base + j]; }
    }
  }
  __syncthreads();
  if (img >= batch) return;            // uniform per wave; no barriers after

  bool a = lane < NCELL;

  // ---- per-lane row reads from LDS ----
  float tv[30], ov[30];
  if (a) {
    const float* Tr = sTf + w * 1470 + lane * 30;
    const float* Or = sOf + w * 1470 + lane * 30;
#pragma unroll
    for (int i = 0; i < 30; ++i) { tv[i] = Tr[i]; ov[i] = Or[i]; }
  } else {
#pragma unroll
    for (int i = 0; i < 30; ++i) { tv[i] = 0.0f; ov[i] = 0.0f; }
  }

  float fjx = (float)(lane % 7), fiy = (float)(lane / 7);

  // ---- ground truth (raw target, no sigmoid) ----
  int gcls = 0; float gx1 = 0, gy1 = 0, gx2 = 0, gy2 = 0; bool gval = false;
  if (a) {
    float tbv = tv[10];
#pragma unroll
    for (int c = 1; c < NCLS; ++c) { float v = tv[10 + c]; if (v > tbv) { tbv = v; gcls = c; } }
    gval = tv[4] > 0.5f;
    float cx = (tv[0] + fjx) * 64.0f, cy = (tv[1] + fiy) * 64.0f;
    float w2 = tv[2] * 448.0f, h2 = tv[3] * 448.0f;
    gx1 = cx - w2 * 0.5f; gy1 = cy - h2 * 0.5f;
    gx2 = cx + w2 * 0.5f; gy2 = cy + h2 * 0.5f;
  }
  unsigned long long gvmask = __ballot(a && gval);

  // ---- gt_count via per-class ballots, one atomic per (wave,class) ----
  {
    int mycnt = 0;
#pragma unroll 1
    for (int c = 0; c < NCLS; ++c) {
      unsigned long long m = __ballot(a && gval && (gcls == c));
      if (lane == c) mycnt = (int)__popcll(m);
    }
    if (lane < NCLS && mycnt) atomicAdd(&gt_count[lane], mycnt);
  }

  // ---- predictions (sigmoid everything, identical formula) ----
  float myc = -1.0f; int myk = 0; float px1 = 0, py1 = 0, px2 = 0, py2 = 0;
  if (a) {
#pragma unroll
    for (int i = 0; i < 30; ++i) ov[i] = sigmoid_ref(ov[i]);
    float c0 = ov[4], c1 = ov[9];
    myc = fmaxf(c0, c1);
    int resp = (c1 > c0) ? 1 : 0;      // first max wins
    float x = ov[resp * 5 + 0], y = ov[resp * 5 + 1];
    float ww = ov[resp * 5 + 2], hh = ov[resp * 5 + 3];
    float obv = ov[10];
#pragma unroll
    for (int c = 1; c < NCLS; ++c) { float v = ov[10 + c]; if (v > obv) { obv = v; myk = c; } }
    float cx = (x + fjx) * 64.0f, cy = (y + fiy) * 64.0f;
    float W = ww * 448.0f, H = hh * 448.0f;
    px1 = cx - W * 0.5f; py1 = cy - H * 0.5f;
    px2 = cx + W * 0.5f; py2 = cy + H * 0.5f;
  }

  // ---- stable rank (argsort(-conf), index tiebreak) via shuffles ----
  int r = lane;
  if (a) {
    r = 0;
#pragma unroll 1
    for (int j = 0; j < NCELL; ++j) {
      float cj = __shfl(myc, j, 64);
      r += (cj > myc) || (cj == myc && j < lane);
    }
  }

  // ---- scatter to rank order ----
  float sx1 = permf(r, px1), sy1 = permf(r, py1);
  float sx2 = permf(r, px2), sy2 = permf(r, py2);
  float sconf = permf(r, myc);
  int   scls  = __builtin_amdgcn_ds_permute(r << 2, myk);
  Box myS; myS.x1 = sx1; myS.y1 = sy1; myS.x2 = sx2; myS.y2 = sy2;

  // ---- greedy class-aware NMS: uniform 64-bit suppression mask ----
  unsigned long long sup = 0;
#pragma unroll 1
  for (int i = 0; i < NCELL; ++i) {
    if ((sup >> i) & 1ull) continue;   // uniform branch
    int ki = __shfl(scls, i, 64);
    Box bi;
    bi.x1 = __shfl(sx1, i, 64); bi.y1 = __shfl(sy1, i, 64);
    bi.x2 = __shfl(sx2, i, 64); bi.y2 = __shfl(sy2, i, 64);
    float v = iou_box(myS, bi);
    bool s = a && (lane > i) && (scls == ki) && (v > 0.5f);
    sup |= __ballot(s);
  }

  bool vp = a && !((sup >> lane) & 1ull) && (sconf > 0.5f);

  // ---- best same-class GT per pred (first-max semantics) ----
  float mx = -1.0f; int best = 0;
#pragma unroll 1
  for (int g = 0; g < NCELL; ++g) {
    if (!((gvmask >> g) & 1ull)) continue;   // uniform branch
    int kg = __shfl(gcls, g, 64);
    Box bg;
    bg.x1 = __shfl(gx1, g, 64); bg.y1 = __shfl(gy1, g, 64);
    bg.x2 = __shfl(gx2, g, 64); bg.y2 = __shfl(gy2, g, 64);
    float v = iou_box(myS, bg);
    bool upd = a && (scls == kg) && (v > mx);
    if (upd) { mx = v; best = g; }
  }

  // ---- greedy TP assignment: uniform, redundant on all lanes ----
  unsigned long long vpmask = __ballot(vp);
  unsigned long long matched = 0, hits = 0;
#pragma unroll 1
  for (int i = 0; i < NCELL; ++i) {
    if (!((vpmask >> i) & 1ull)) continue;   // uniform
    float mxi = __shfl(mx, i, 64);
    int   bi  = __shfl(best, i, 64);
    if ((mxi > 0.5f) && !((matched >> bi) & 1ull)) {
      matched |= 1ull << bi;
      hits    |= 1ull << i;
    }
  }

  if (a) {
    entries[(size_t)img * NCELL + lane] =
        (uint8_t)(scls | (vp ? 32 : 0) | (((hits >> lane) & 1ull) ? 64 : 0));
  }
}

// Exact per-byte match: y bytes < 0x40, so per-byte (y+0x7f) sets bit7 iff
// y>=1 with NO cross-byte carry. m has 0x80 exactly where (b&0x3f)==want.
__device__ __forceinline__ unsigned match_mask(unsigned w, unsigned wantx4) {
  unsigned y = (w & 0x3f3f3f3fu) ^ wantx4;
  return ~(y + 0x7f7f7f7fu) & 0x80808080u;
}

__device__ __forceinline__ uint4 load_tile(const uint8_t* entries, int e, int e1, int ne) {
  uint4 w4 = make_uint4(0, 0, 0, 0);
  if (e < e1) {
    int p = e << 4;
    if (p + 16 <= ne) {
      w4 = *(const uint4*)(entries + p);
    } else {
      unsigned ws[4] = {0, 0, 0, 0};
      for (int k = 0; k < ne - p; ++k)
        ws[k >> 2] |= ((unsigned)entries[p + k]) << (8 * (k & 3));
      w4.x = ws[0]; w4.y = ws[1]; w4.z = ws[2]; w4.w = ws[3];
    }
  }
  return w4;
}

// Stage A: per-(class,segment) (valid, tp) totals. Grid = NCLS*NSEG blocks.
__global__ __launch_bounds__(256) void k_apA(
    const uint8_t* __restrict__ entries, uint2* __restrict__ totals, int ne)
{
  int c = blockIdx.x / NSEG, s = blockIdx.x % NSEG;
  int tid = threadIdx.x, wid = tid >> 6, lane = tid & 63;
  unsigned wantx4 = (32u + (unsigned)c) * 0x01010101u;

  int nel = (ne + 15) >> 4;
  int segel = (nel + NSEG - 1) / NSEG;
  int se0 = s * segel;
  int se1 = se0 + segel; if (se1 > nel) se1 = nel;
  int elw = (se1 > se0) ? ((se1 - se0 + 3) >> 2) : 0;
  int e0 = se0 + wid * elw;
  int e1 = e0 + elw; if (e1 > se1) e1 = se1;
  int ntile = (e1 > e0) ? ((e1 - e0 + 63) >> 6) : 0;

  unsigned mv = 0, mt = 0;
  for (int t = 0; t < ntile; ++t) {
    uint4 w4 = load_tile(entries, e0 + t * 64 + lane, e1, ne);
    unsigned wsv[4] = {w4.x, w4.y, w4.z, w4.w};
#pragma unroll
    for (int q = 0; q < 4; ++q) {
      unsigned m = match_mask(wsv[q], wantx4);
      mv += __popc(m);
      mt += __popc(m & (wsv[q] << 1));
    }
  }
  unsigned long long tot = ((unsigned long long)mv << 32) | (unsigned long long)mt;
#pragma unroll
  for (int d = 1; d < 64; d <<= 1) tot += __shfl_xor(tot, d, 64);
  __shared__ unsigned long long wt[4];
  if (lane == 0) wt[wid] = tot;
  __syncthreads();
  if (tid == 0) {
    unsigned long long T = wt[0] + wt[1] + wt[2] + wt[3];
    totals[blockIdx.x] = make_uint2((unsigned)(T >> 32), (unsigned)(T & 0xffffffffull));
  }
}

// Stage B: emit trapezoid terms with exact global running ranks.
__global__ __launch_bounds__(256) void k_apB(
    const uint8_t* __restrict__ entries, const uint2* __restrict__ totals,
    const int* __restrict__ gt_count, double* __restrict__ partials, int ne)
{
#pragma clang fp contract(off)
  int c = blockIdx.x / NSEG, s = blockIdx.x % NSEG;
  int tid = threadIdx.x, wid = tid >> 6, lane = tid & 63;
  float g2 = (float)gt_count[c] + 1e-6f;
  unsigned wantx4 = (32u + (unsigned)c) * 0x01010101u;

  int nel = (ne + 15) >> 4;
  int segel = (nel + NSEG - 1) / NSEG;
  int se0 = s * segel;
  int se1 = se0 + segel; if (se1 > nel) se1 = nel;
  int elw = (se1 > se0) ? ((se1 - se0 + 3) >> 2) : 0;
  int e0 = se0 + wid * elw;
  int e1 = e0 + elw; if (e1 > se1) e1 = se1;
  int ntile = (e1 > e0) ? ((e1 - e0 + 63) >> 6) : 0;

  // global prefix from earlier segments of this class
  unsigned Jrun = 0, Trun = 0;
  for (int s2 = 0; s2 < s; ++s2) {
    uint2 t2 = totals[c * NSEG + s2];
    Jrun += t2.x; Trun += t2.y;
  }

  // local phase A: per-wave totals within segment -> wave offsets
  unsigned mv = 0, mt = 0;
  for (int t = 0; t < ntile; ++t) {
    uint4 w4 = load_tile(entries, e0 + t * 64 + lane, e1, ne);
    unsigned wsv[4] = {w4.x, w4.y, w4.z, w4.w};
#pragma unroll
    for (int q = 0; q < 4; ++q) {
      unsigned m = match_mask(wsv[q], wantx4);
      mv += __popc(m);
      mt += __popc(m & (wsv[q] << 1));
    }
  }
  unsigned long long tot = ((unsigned long long)mv << 32) | (unsigned long long)mt;
#pragma unroll
  for (int d = 1; d < 64; d <<= 1) tot += __shfl_xor(tot, d, 64);
  __shared__ unsigned long long wt[4];
  __shared__ double wacc[4];
  if (lane == 0) wt[wid] = tot;
  __syncthreads();
  for (int w2 = 0; w2 < wid; ++w2) {
    Jrun += (unsigned)(wt[w2] >> 32);
    Trun += (unsigned)(wt[w2] & 0xffffffffull);
  }

  // phase B: per-tile bit-plane prefix + sparse emit
  double acc = 0.0;
  for (int t = 0; t < ntile; ++t) {
    int e = e0 + t * 64 + lane;
    int p = e << 4;
    uint4 w4 = load_tile(entries, e, e1, ne);
    unsigned wsv[4] = {w4.x, w4.y, w4.z, w4.w};
    unsigned mm[4], tm[4];
    unsigned cv = 0, ct = 0;
#pragma unroll
    for (int q = 0; q < 4; ++q) {
      unsigned m = match_mask(wsv[q], wantx4);
      mm[q] = m; tm[q] = m & (wsv[q] << 1);
      cv += __popc(m); ct += __popc(tm[q]);
    }
    unsigned jexcl = 0, texcl = 0, jtt = 0, ttt = 0;
#pragma unroll
    for (int b = 0; b < 5; ++b) {
      unsigned long long mj = __ballot(((cv >> b) & 1u) != 0u);
      unsigned long long mk = __ballot(((ct >> b) & 1u) != 0u);
      jexcl += mbcnt64(mj) << b;
      texcl += mbcnt64(mk) << b;
      jtt   += (unsigned)__popcll(mj) << b;
      ttt   += (unsigned)__popcll(mk) << b;
    }
    unsigned jr = Jrun + jexcl;
    unsigned tr = Trun + texcl;
#pragma unroll
    for (int q = 0; q < 4; ++q) {
      unsigned m = mm[q];
      while (m) {
        unsigned bit = (unsigned)__builtin_ctz(m);
        m &= m - 1;
        ++jr;
        if (tm[q] & (1u << bit)) {
          ++tr;
          int pos = p + 4 * q + (int)(bit >> 3);
          float ft = (float)tr, fj = (float)jr;
          float r_cur  = ft / g2;
          float r_prev = (ft - 1.0f) / g2;
          float p_cur  = ft / (fj + 1e-6f);
          float p_prev = (pos == 0) ? 1.0f
                                    : (ft - 1.0f) / ((fj - 1.0f) + 1e-6f);
          acc += (double)((r_cur - r_prev) * (p_cur + p_prev) * 0.5f);
        }
      }
    }
    Jrun += jtt;
    Trun += ttt;
  }

  for (int d = 32; d > 0; d >>= 1) acc += __shfl_down(acc, d, 64);
  if (lane == 0) wacc[wid] = acc;
  __syncthreads();
  if (tid == 0) partials[blockIdx.x] = wacc[0] + wacc[1] + wacc[2] + wacc[3];
}

__global__ void k_final(const double* __restrict__ partials,
                        const int* __restrict__ gt_count,
                        float* __restrict__ out)
{
#pragma clang fp contract(off)
  __shared__ float apf[NCLS];
  int t = threadIdx.x;
  if (t < NCLS) {
    double s = 0.0;
#pragma unroll
    for (int i = 0; i < NSEG; ++i) s += partials[t * NSEG + i];
    apf[t] = (float)s;
  }
  __syncthreads();
  if (t == 0) {
    float s = 0.0f, n = 0.0f;
    for (int c = 0; c < NCLS; ++c) {
      if (gt_count[c] > 0) { s += apf[c]; n += 1.0f; }
    }
    float nh = fmaxf(n, 1.0f);
    out[0] = s / nh;
  }
}

extern "C" void kernel_launch(void* const* d_in, const int* in_sizes, int n_in,
                              void* d_out, int out_size, void* d_ws, size_t ws_size,
                              hipStream_t stream) {
  const float* target = (const float*)d_in[0];
  const float* output = (const float*)d_in[1];
  int batch = in_sizes[0] / (NCELL * 30);
  int ne = batch * NCELL;

  uint8_t* entries = (uint8_t*)d_ws;
  size_t offA = ((size_t)ne + 255) & ~(size_t)255;
  int*    gt_count = (int*)((char*)d_ws + offA);
  uint2*  totals   = (uint2*)((char*)d_ws + offA + 256);
  double* partials = (double*)((char*)d_ws + offA + 256 + 4096);

  (void)hipMemsetAsync(gt_count, 0, 64 * sizeof(int), stream);
  k_per_image<<<(batch + 3) / 4, 256, 0, stream>>>(target, output, entries, gt_count, batch);
  k_apA<<<NCLS * NSEG, 256, 0, stream>>>(entries, totals, ne);
  k_apB<<<NCLS * NSEG, 256, 0, stream>>>(entries, totals, gt_count, partials, ne);
  k_final<<<1, 64, 0, stream>>>(partials, gt_count, (float*)d_out);
}